// Round 1
// baseline (2225.808 us; speedup 1.0000x reference)
//
#include <hip/hip_runtime.h>
#include <stdint.h>

// ---- PRNG mode: 1 = jax_threefry_partitionable (default in jax >= 0.5),
//                 0 = original threefry stream layout
#ifndef PRNG_PARTITIONABLE
#define PRNG_PARTITIONABLE 1
#endif

#define ONE_M_U 0.99999994039535522461f   // 1 - 2^-24 (0x3F7FFFFF)

// ---------------- threefry2x32 (exact JAX rounds) ----------------
__device__ __forceinline__ void tf_4a(uint32_t& x0, uint32_t& x1){
  x0 += x1; x1 = (x1<<13)|(x1>>19); x1 ^= x0;
  x0 += x1; x1 = (x1<<15)|(x1>>17); x1 ^= x0;
  x0 += x1; x1 = (x1<<26)|(x1>>6);  x1 ^= x0;
  x0 += x1; x1 = (x1<<6) |(x1>>26); x1 ^= x0;
}
__device__ __forceinline__ void tf_4b(uint32_t& x0, uint32_t& x1){
  x0 += x1; x1 = (x1<<17)|(x1>>15); x1 ^= x0;
  x0 += x1; x1 = (x1<<29)|(x1>>3);  x1 ^= x0;
  x0 += x1; x1 = (x1<<16)|(x1>>16); x1 ^= x0;
  x0 += x1; x1 = (x1<<24)|(x1>>8);  x1 ^= x0;
}
__device__ __forceinline__ void threefry2x32(uint32_t k0, uint32_t k1, uint32_t& x0, uint32_t& x1){
  uint32_t k2 = k0 ^ k1 ^ 0x1BD11BDAu;
  x0 += k0; x1 += k1;
  tf_4a(x0,x1); x0 += k1; x1 += k2 + 1u;
  tf_4b(x0,x1); x0 += k2; x1 += k0 + 2u;
  tf_4a(x0,x1); x0 += k0; x1 += k1 + 3u;
  tf_4b(x0,x1); x0 += k1; x1 += k2 + 4u;
  tf_4a(x0,x1); x0 += k2; x1 += k0 + 5u;
}

// jax _uniform bit manipulation, minval=-1 maxval=1 (all steps exact in f32)
__device__ __forceinline__ float bits_to_unit(uint32_t b){
  #pragma clang fp contract(off)
  float f = __uint_as_float((b >> 9) | 0x3f800000u) - 1.0f;
  float r = f * 2.0f + (-1.0f);
  return __builtin_fmaxf(-1.0f, r);
}

// XLA elemental_ir_emitter EmitTanh f32: clamp +-9, rational, |x|<4e-4 -> x.
// Plain mul/add (XLA emits unfused FMul/FAdd) -> contract off.
__device__ __forceinline__ float xla_tanh_f32(float x){
  #pragma clang fp contract(off)
  float ax = __builtin_fabsf(x);
  float xc = __builtin_fminf(__builtin_fmaxf(x, -9.0f), 9.0f);
  float x2 = xc * xc;
  float nm = -2.76076847742355e-16f;
  nm = x2 * nm + 2.00018790482477e-13f;
  nm = x2 * nm + -8.60467152213735e-11f;
  nm = x2 * nm + 5.12229709037114e-08f;
  nm = x2 * nm + 1.48572235717979e-05f;
  nm = x2 * nm + 6.37261928875436e-04f;
  nm = x2 * nm + 4.89352455891786e-03f;
  nm = xc * nm;
  float dn = 1.19825839466702e-06f;
  dn = x2 * dn + 1.18534705686654e-04f;
  dn = x2 * dn + 2.26843463243900e-03f;
  dn = x2 * dn + 4.89352518554385e-03f;
  float res = nm / dn;
  return (ax < 0.0004f) ? x : res;
}

// k-ascending fused-multiply-add chain, acc init 0 (Eigen/XLA dot semantics).
// stream values are {+-1, +-(1-2^-24)} encoded in (sw,dw) bit k.
__device__ __forceinline__ float dot64(unsigned long long sw, unsigned long long dw,
                                       const float* w){
  float acc = 0.0f;
  #pragma unroll
  for (int k = 0; k < 64; ++k){
    float mag = ((dw >> k) & 1ull) ? ONE_M_U : 1.0f;
    float p   = ((sw >> k) & 1ull) ? mag : -mag;
    acc = __builtin_fmaf(p, w[k], acc);
  }
  return acc;
}

// -------- workspace layout (bytes) --------
#define QW_OFF   0u          // float[9][128][64]
#define SGN_OFF  294912u     // u64[32][9][1024]
#define DIM_OFF  2654208u    // u64[32][9][1024]
#define KEYS_OFF 5013504u    // u32[18]
#define MV_OFF   5013632u    // float[9*128][2]  (mean, sqrt(var+eps))

// ================= K1: weight standardize + quantize + PRNG keys =================
__global__ __launch_bounds__(64) void k_weights(const float* __restrict__ W,
        float* __restrict__ qw, uint32_t* __restrict__ keys){
  #pragma clang fp contract(off)
  __shared__ float  bwL[576];
  __shared__ double red[64];
  int o = blockIdx.x, t = threadIdx.x;
  double s = 0.0;
  for (int j = t; j < 576; j += 64) s += (double)W[o*576 + j];
  red[t] = s; __syncthreads();
  for (int k = 32; k > 0; k >>= 1){ if (t < k) red[t] += red[t+k]; __syncthreads(); }
  float mean1 = (float)(red[0] / 576.0);
  __syncthreads();
  for (int j = t; j < 576; j += 64) bwL[j] = W[o*576 + j] - mean1;
  __syncthreads();
  s = 0.0;
  for (int j = t; j < 576; j += 64) s += (double)bwL[j];
  red[t] = s; __syncthreads();
  for (int k = 32; k > 0; k >>= 1){ if (t < k) red[t] += red[t+k]; __syncthreads(); }
  float mean2 = (float)(red[0] / 576.0);
  __syncthreads();
  s = 0.0;
  for (int j = t; j < 576; j += 64){ float c = bwL[j] - mean2; float sq = c * c; s += (double)sq; }
  red[t] = s; __syncthreads();
  for (int k = 32; k > 0; k >>= 1){ if (t < k) red[t] += red[t+k]; __syncthreads(); }
  float varf = (float)(red[0] / 575.0);          // ddof=1
  float stdv = __builtin_sqrtf(varf);
  __syncthreads();
  for (int j = t; j < 576; j += 64){
    float b2 = bwL[j] / stdv;
    float c  = __builtin_fminf(__builtin_fmaxf(b2, -1.0f), 1.0f);
    float q  = __builtin_rintf(c * 7.0f) / 7.0f; // round-half-even, f32 div
    float fwd = c + (q - c);                     // STE forward, exact f32 ops
    int g = j >> 6, k = j & 63;
    qw[(g*128 + o)*64 + k] = fwd;
  }
  if (o == 0 && t == 0){
#if PRNG_PARTITIONABLE
    for (int g = 0; g < 9; ++g){
      uint32_t x0 = 0u, x1 = (uint32_t)g;
      threefry2x32(0u, 42u, x0, x1);
      keys[2*g] = x0; keys[2*g+1] = x1;
    }
#else
    uint32_t outv[18];
    for (int i = 0; i < 9; ++i){
      uint32_t x0 = (uint32_t)i, x1 = (uint32_t)(9 + i);
      threefry2x32(0u, 42u, x0, x1);
      outv[i] = x0; outv[9+i] = x1;
    }
    for (int j = 0; j < 18; ++j) keys[j] = outv[j];
#endif
  }
}

// ================= K2: unfold + clip + residual sign planes (2-bit packed) ============
__global__ __launch_bounds__(256) void k_stream(const float* __restrict__ X,
        unsigned long long* __restrict__ sgn, unsigned long long* __restrict__ dimw){
  #pragma clang fp contract(off)
  int tid = blockIdx.x * 256 + threadIdx.x;   // 0..8191
  int b = tid >> 10, l = tid & 1023;
  int h = l >> 5, w = l & 31;
  unsigned long long sw[36] = {0ull}, dw[36] = {0ull};
  const float hp[4] = {0.5f, 0.25f, 0.125f, 0.0625f};
  for (int c = 0; c < 64; ++c){
    for (int kp = 0; kp < 9; ++kp){
      int di = kp / 3 - 1, dj = kp % 3 - 1;
      int hh = h + di, ww = w + dj;
      float v = 0.0f;
      if (hh >= 0 && hh < 32 && ww >= 0 && ww < 32)
        v = X[((b*64 + c)*32 + hh)*32 + ww];
      float x = __builtin_fminf(__builtin_fmaxf(v, -1.0f), 1.0f);
      float r = x;
      int ck = c*9 + kp, g = ck >> 6, kk = ck & 63;
      #pragma unroll
      for (int a = 0; a < 4; ++a){
        float sv = (r >= 0.0f) ? 1.0f : -1.0f;
        float d  = sv - x;        // f32
        float p  = x + d;         // plane forward value: +-1 or +-(1-2^-24)
        int idx = a*9 + g;
        if (sv > 0.0f) sw[idx] |= (1ull << kk);
        if (__builtin_fabsf(p) < 1.0f) dw[idx] |= (1ull << kk);
        r = r - sv * hp[a];
      }
    }
  }
  for (int a = 0; a < 4; ++a){
    int n = a*8 + b;
    for (int g = 0; g < 9; ++g){
      sgn [(n*9 + g)*1024 + l] = sw[a*9+g];
      dimw[(n*9 + g)*1024 + l] = dw[a*9+g];
    }
  }
}

// ================= K3: BN train-mode stats per (g,o), f64 reduction =================
__global__ __launch_bounds__(256) void k_stats(const float* __restrict__ qw,
        const unsigned long long* __restrict__ sgn, const unsigned long long* __restrict__ dimw,
        float* __restrict__ mv){
  #pragma clang fp contract(off)
  __shared__ double red[256];
  int g = blockIdx.x >> 7, o = blockIdx.x & 127, t = threadIdx.x;
  float wr[64];
  #pragma unroll
  for (int k = 0; k < 64; ++k) wr[k] = qw[(g*128 + o)*64 + k];
  double s1 = 0.0;
  for (int n = 0; n < 32; ++n){
    const unsigned long long* sp = sgn  + (n*9 + g)*1024;
    const unsigned long long* dp = dimw + (n*9 + g)*1024;
    for (int j = 0; j < 4; ++j){
      int l = t + j*256;
      float tv = dot64(sp[l], dp[l], wr);
      s1 += (double)tv;
    }
  }
  red[t] = s1; __syncthreads();
  for (int k = 128; k > 0; k >>= 1){ if (t < k) red[t] += red[t+k]; __syncthreads(); }
  float mean = (float)(red[0] / 32768.0);
  __syncthreads();
  double s2 = 0.0;
  for (int n = 0; n < 32; ++n){
    const unsigned long long* sp = sgn  + (n*9 + g)*1024;
    const unsigned long long* dp = dimw + (n*9 + g)*1024;
    for (int j = 0; j < 4; ++j){
      int l = t + j*256;
      float tv = dot64(sp[l], dp[l], wr);
      float c = tv - mean;      // f32, as ref
      float sq = c * c;         // f32 square, as ref
      s2 += (double)sq;
    }
  }
  red[t] = s2; __syncthreads();
  for (int k = 128; k > 0; k >>= 1){ if (t < k) red[t] += red[t+k]; __syncthreads(); }
  if (t == 0){
    float var = (float)(red[0] / 32768.0);
    float den = __builtin_sqrtf(var + 1e-5f);
    mv[(g*128+o)*2]   = mean;
    mv[(g*128+o)*2+1] = den;
  }
}

// ================= K5: decisions + exact f32 recombination =================
__global__ __launch_bounds__(256) void k_out(const float* __restrict__ qw,
        const unsigned long long* __restrict__ sgn, const unsigned long long* __restrict__ dimw,
        const float* __restrict__ mv, const uint32_t* __restrict__ keys,
        const float* __restrict__ gamma, const float* __restrict__ beta,
        float* __restrict__ out){
  #pragma clang fp contract(off)
  __shared__ float    wv[576];
  __shared__ float    mvL[18];
  __shared__ uint32_t kL[18];
  int bi = blockIdx.x;                  // 4096 = 8 b * 128 o * 4 lc
  int lc = bi & 3, o = (bi >> 2) & 127, b = bi >> 9;
  int t = threadIdx.x;
  for (int j = t; j < 576; j += 256) wv[j] = qw[((j >> 6)*128 + o)*64 + (j & 63)];
  if (t < 18){ mvL[t] = mv[((t>>1)*128 + o)*2 + (t&1)]; kL[t] = keys[t]; }
  __syncthreads();
  int l = lc*256 + t;
  float gma = gamma[o], bta = beta[o];
  float S[4] = {0.0f, 0.0f, 0.0f, 0.0f};
  for (int g = 0; g < 9; ++g){
    float rnd[4];
#if PRNG_PARTITIONABLE
    #pragma unroll
    for (int a = 0; a < 4; ++a){
      uint32_t m = (uint32_t)((a*8 + b)*131072 + o*1024 + l);
      uint32_t x0 = 0u, x1 = m;
      threefry2x32(kL[2*g], kL[2*g+1], x0, x1);
      rnd[a] = bits_to_unit(x0 ^ x1);
    }
#else
    #pragma unroll
    for (int a01 = 0; a01 < 2; ++a01){
      uint32_t m = (uint32_t)((a01*8 + b)*131072 + o*1024 + l);
      uint32_t x0 = m, x1 = m + 2097152u;
      threefry2x32(kL[2*g], kL[2*g+1], x0, x1);
      rnd[a01]     = bits_to_unit(x0);
      rnd[a01 + 2] = bits_to_unit(x1);
    }
#endif
    float mean = mvL[2*g], den = mvL[2*g+1];
    float wr[64];
    #pragma unroll
    for (int k = 0; k < 64; ++k) wr[k] = wv[g*64 + k];
    #pragma unroll
    for (int a = 0; a < 4; ++a){
      int n = a*8 + b;
      float tv = dot64(sgn[(n*9+g)*1024 + l], dimw[(n*9+g)*1024 + l], wr);
      float normed = (tv - mean) / den * gma + bta;   // f32 div, mul, add (unfused)
      float th = xla_tanh_f32(4.0f * normed);
      float dec = (th > rnd[a]) ? 1.0f : -1.0f;
      if (normed == 0.0f) dec = 0.0f;
      float cc  = __builtin_fminf(__builtin_fmaxf(normed, -1.0f), 1.0f);
      float fwd = cc + (dec - cc);                    // mtj STE forward, exact f32 ops
      float pre = fwd / 9.0f;                         // f32 division by NUM_CHUNKS
      S[a] = S[a] + pre;                              // g-ascending f32 chain (XLA reduce order)
    }
  }
  float z = S[0] * 0.5f;      // (out*wts).sum(0): a-ascending f32 chain, pow2 mults exact
  z = z + S[1] * 0.25f;
  z = z + S[2] * 0.125f;
  z = z + S[3] * 0.0625f;
  out[(b*128 + o)*1024 + l] = z;
}

extern "C" void kernel_launch(void* const* d_in, const int* in_sizes, int n_in,
                              void* d_out, int out_size, void* d_ws, size_t ws_size,
                              hipStream_t stream){
  (void)in_sizes; (void)n_in; (void)out_size; (void)ws_size;
  const float* inp   = (const float*)d_in[0];
  const float* wgt   = (const float*)d_in[1];
  const float* gamma = (const float*)d_in[2];
  const float* beta  = (const float*)d_in[3];
  float* out = (float*)d_out;
  char* ws = (char*)d_ws;
  float*              qw   = (float*)(ws + QW_OFF);
  unsigned long long* sgn  = (unsigned long long*)(ws + SGN_OFF);
  unsigned long long* dimw = (unsigned long long*)(ws + DIM_OFF);
  uint32_t*           keys = (uint32_t*)(ws + KEYS_OFF);
  float*              mv   = (float*)(ws + MV_OFF);

  hipLaunchKernelGGL(k_weights, dim3(128),  dim3(64),  0, stream, wgt, qw, keys);
  hipLaunchKernelGGL(k_stream,  dim3(32),   dim3(256), 0, stream, inp, sgn, dimw);
  hipLaunchKernelGGL(k_stats,   dim3(1152), dim3(256), 0, stream, qw, sgn, dimw, mv);
  hipLaunchKernelGGL(k_out,     dim3(4096), dim3(256), 0, stream, qw, sgn, dimw, mv, keys,
                     gamma, beta, out);
}

// Round 2
// 1103.433 us; speedup vs baseline: 2.0172x; 2.0172x over previous
//
#include <hip/hip_runtime.h>
#include <stdint.h>

// ---- PRNG mode: 1 = jax_threefry_partitionable (default in jax >= 0.5)
#ifndef PRNG_PARTITIONABLE
#define PRNG_PARTITIONABLE 1
#endif

#define ONE_M_U 0.99999994039535522461f   // 1 - 2^-24 (0x3F7FFFFF)

// ---------------- threefry2x32 (exact JAX rounds) ----------------
__device__ __forceinline__ void tf_4a(uint32_t& x0, uint32_t& x1){
  x0 += x1; x1 = (x1<<13)|(x1>>19); x1 ^= x0;
  x0 += x1; x1 = (x1<<15)|(x1>>17); x1 ^= x0;
  x0 += x1; x1 = (x1<<26)|(x1>>6);  x1 ^= x0;
  x0 += x1; x1 = (x1<<6) |(x1>>26); x1 ^= x0;
}
__device__ __forceinline__ void tf_4b(uint32_t& x0, uint32_t& x1){
  x0 += x1; x1 = (x1<<17)|(x1>>15); x1 ^= x0;
  x0 += x1; x1 = (x1<<29)|(x1>>3);  x1 ^= x0;
  x0 += x1; x1 = (x1<<16)|(x1>>16); x1 ^= x0;
  x0 += x1; x1 = (x1<<24)|(x1>>8);  x1 ^= x0;
}
__device__ __forceinline__ void threefry2x32(uint32_t k0, uint32_t k1, uint32_t& x0, uint32_t& x1){
  uint32_t k2 = k0 ^ k1 ^ 0x1BD11BDAu;
  x0 += k0; x1 += k1;
  tf_4a(x0,x1); x0 += k1; x1 += k2 + 1u;
  tf_4b(x0,x1); x0 += k2; x1 += k0 + 2u;
  tf_4a(x0,x1); x0 += k0; x1 += k1 + 3u;
  tf_4b(x0,x1); x0 += k1; x1 += k2 + 4u;
  tf_4a(x0,x1); x0 += k2; x1 += k0 + 5u;
}

__device__ __forceinline__ float bits_to_unit(uint32_t b){
  #pragma clang fp contract(off)
  float f = __uint_as_float((b >> 9) | 0x3f800000u) - 1.0f;
  float r = f * 2.0f + (-1.0f);
  return __builtin_fmaxf(-1.0f, r);
}

// XLA elemental_ir_emitter EmitTanh f32 (unfused mul/add)
__device__ __forceinline__ float xla_tanh_f32(float x){
  #pragma clang fp contract(off)
  float ax = __builtin_fabsf(x);
  float xc = __builtin_fminf(__builtin_fmaxf(x, -9.0f), 9.0f);
  float x2 = xc * xc;
  float nm = -2.76076847742355e-16f;
  nm = x2 * nm + 2.00018790482477e-13f;
  nm = x2 * nm + -8.60467152213735e-11f;
  nm = x2 * nm + 5.12229709037114e-08f;
  nm = x2 * nm + 1.48572235717979e-05f;
  nm = x2 * nm + 6.37261928875436e-04f;
  nm = x2 * nm + 4.89352455891786e-03f;
  nm = xc * nm;
  float dn = 1.19825839466702e-06f;
  dn = x2 * dn + 1.18534705686654e-04f;
  dn = x2 * dn + 2.26843463243900e-03f;
  dn = x2 * dn + 4.89352518554385e-03f;
  float res = nm / dn;
  return (ax < 0.0004f) ? x : res;
}

// k-ascending fma chain (fallback path only)
__device__ __forceinline__ float dot64(unsigned long long sw, unsigned long long dw,
                                       const float* w){
  float acc = 0.0f;
  #pragma unroll
  for (int k = 0; k < 64; ++k){
    float mag = ((dw >> k) & 1ull) ? ONE_M_U : 1.0f;
    float p   = ((sw >> k) & 1ull) ? mag : -mag;
    acc = __builtin_fmaf(p, w[k], acc);
  }
  return acc;
}

// -------- workspace layout (bytes) --------
#define QW_OFF   0u           // float[9][128][64]   ([g][o][k])
#define QWT_OFF  294912u      // float[9][64][128]   ([g][k][o])
#define SGN_OFF  589824u      // u64[32][9][1024]
#define DIM_OFF  2949120u     // u64[32][9][1024]
#define KEYS_OFF 5308416u     // u32[18]
#define MV_OFF   5308544u     // float[9*128][2]
#define LT_OFF   5318656u     // float[32][9][128][1024]  (fast path only)
#define LT_BYTES 150994944u
#define WS_NEEDED_FAST (LT_OFF + LT_BYTES)

// ================= K1: weight standardize + quantize + PRNG keys =================
__global__ __launch_bounds__(64) void k_weights(const float* __restrict__ W,
        float* __restrict__ qw, float* __restrict__ qwT, uint32_t* __restrict__ keys){
  #pragma clang fp contract(off)
  __shared__ float  bwL[576];
  __shared__ double red[64];
  int o = blockIdx.x, t = threadIdx.x;
  double s = 0.0;
  for (int j = t; j < 576; j += 64) s += (double)W[o*576 + j];
  red[t] = s; __syncthreads();
  for (int k = 32; k > 0; k >>= 1){ if (t < k) red[t] += red[t+k]; __syncthreads(); }
  float mean1 = (float)(red[0] / 576.0);
  __syncthreads();
  for (int j = t; j < 576; j += 64) bwL[j] = W[o*576 + j] - mean1;
  __syncthreads();
  s = 0.0;
  for (int j = t; j < 576; j += 64) s += (double)bwL[j];
  red[t] = s; __syncthreads();
  for (int k = 32; k > 0; k >>= 1){ if (t < k) red[t] += red[t+k]; __syncthreads(); }
  float mean2 = (float)(red[0] / 576.0);
  __syncthreads();
  s = 0.0;
  for (int j = t; j < 576; j += 64){ float c = bwL[j] - mean2; float sq = c * c; s += (double)sq; }
  red[t] = s; __syncthreads();
  for (int k = 32; k > 0; k >>= 1){ if (t < k) red[t] += red[t+k]; __syncthreads(); }
  float varf = (float)(red[0] / 575.0);
  float stdv = __builtin_sqrtf(varf);
  __syncthreads();
  for (int j = t; j < 576; j += 64){
    float b2 = bwL[j] / stdv;
    float c  = __builtin_fminf(__builtin_fmaxf(b2, -1.0f), 1.0f);
    float q  = __builtin_rintf(c * 7.0f) / 7.0f;
    float fwd = c + (q - c);
    int g = j >> 6, k = j & 63;
    qw [(g*128 + o)*64 + k] = fwd;
    qwT[(g*64  + k)*128 + o] = fwd;
  }
  if (o == 0 && t == 0){
#if PRNG_PARTITIONABLE
    for (int g = 0; g < 9; ++g){
      uint32_t x0 = 0u, x1 = (uint32_t)g;
      threefry2x32(0u, 42u, x0, x1);
      keys[2*g] = x0; keys[2*g+1] = x1;
    }
#else
    uint32_t outv[18];
    for (int i = 0; i < 9; ++i){
      uint32_t x0 = (uint32_t)i, x1 = (uint32_t)(9 + i);
      threefry2x32(0u, 42u, x0, x1);
      outv[i] = x0; outv[9+i] = x1;
    }
    for (int j = 0; j < 18; ++j) keys[j] = outv[j];
#endif
  }
}

// ================= K2: unfold + clip + residual sign planes (2-bit packed) ============
__global__ __launch_bounds__(256) void k_stream(const float* __restrict__ X,
        unsigned long long* __restrict__ sgn, unsigned long long* __restrict__ dimw){
  #pragma clang fp contract(off)
  int tid = blockIdx.x * 256 + threadIdx.x;   // 0..8191
  int b = tid >> 10, l = tid & 1023;
  int h = l >> 5, w = l & 31;
  unsigned long long sw[36] = {0ull}, dw[36] = {0ull};
  const float hp[4] = {0.5f, 0.25f, 0.125f, 0.0625f};
  for (int c = 0; c < 64; ++c){
    for (int kp = 0; kp < 9; ++kp){
      int di = kp / 3 - 1, dj = kp % 3 - 1;
      int hh = h + di, ww = w + dj;
      float v = 0.0f;
      if (hh >= 0 && hh < 32 && ww >= 0 && ww < 32)
        v = X[((b*64 + c)*32 + hh)*32 + ww];
      float x = __builtin_fminf(__builtin_fmaxf(v, -1.0f), 1.0f);
      float r = x;
      int ck = c*9 + kp, g = ck >> 6, kk = ck & 63;
      #pragma unroll
      for (int a = 0; a < 4; ++a){
        float sv = (r >= 0.0f) ? 1.0f : -1.0f;
        float d  = sv - x;
        float p  = x + d;
        int idx = a*9 + g;
        if (sv > 0.0f) sw[idx] |= (1ull << kk);
        if (__builtin_fabsf(p) < 1.0f) dw[idx] |= (1ull << kk);
        r = r - sv * hp[a];
      }
    }
  }
  for (int a = 0; a < 4; ++a){
    int n = a*8 + b;
    for (int g = 0; g < 9; ++g){
      sgn [(n*9 + g)*1024 + l] = sw[a*9+g];
      dimw[(n*9 + g)*1024 + l] = dw[a*9+g];
    }
  }
}

// ================= K_GEMM: decode-once register-blocked GEMM -> lt =================
// block: fixed (n, g, lchunk of 64 l); thread tile 4o x 8l; k-ascending fma from 0
__global__ __launch_bounds__(256) void k_gemm(const float* __restrict__ qwT,
        const unsigned long long* __restrict__ sgn, const unsigned long long* __restrict__ dimw,
        float* __restrict__ lt){
  __shared__ float wT[64*128];   // [k][o]
  __shared__ float pL[64*64];    // [k][lc]
  int lchunk = blockIdx.x, g = blockIdx.y, n = blockIdx.z;
  int t = threadIdx.x;
  for (int j = t; j < 8192; j += 256) wT[j] = qwT[g*8192 + j];  // j = k*128+o, coalesced
  {
    int lc = t & 63, kq = t >> 6;
    unsigned long long sw = sgn [(n*9+g)*1024 + lchunk*64 + lc];
    unsigned long long dw = dimw[(n*9+g)*1024 + lchunk*64 + lc];
    #pragma unroll
    for (int kk = 0; kk < 16; ++kk){
      int k = kq*16 + kk;
      float mag = ((dw >> k) & 1ull) ? ONE_M_U : 1.0f;
      float p   = ((sw >> k) & 1ull) ? mag : -mag;
      pL[k*64 + lc] = p;
    }
  }
  __syncthreads();
  int otile = t & 31, ltile = t >> 5;
  const float4* wT4 = (const float4*)wT;
  const float4* pL4 = (const float4*)pL;
  float acc[4][8];
  #pragma unroll
  for (int i = 0; i < 4; ++i)
    #pragma unroll
    for (int j = 0; j < 8; ++j) acc[i][j] = 0.0f;
  #pragma unroll 8
  for (int k = 0; k < 64; ++k){
    float4 wv = wT4[k*32 + otile];
    float4 pa = pL4[k*16 + ltile*2];
    float4 pb = pL4[k*16 + ltile*2 + 1];
    float wr[4] = {wv.x, wv.y, wv.z, wv.w};
    float pr[8] = {pa.x, pa.y, pa.z, pa.w, pb.x, pb.y, pb.z, pb.w};
    #pragma unroll
    for (int i = 0; i < 4; ++i)
      #pragma unroll
      for (int j = 0; j < 8; ++j)
        acc[i][j] = __builtin_fmaf(pr[j], wr[i], acc[i][j]);
  }
  int o0 = otile*4, l0 = lchunk*64 + ltile*8;
  #pragma unroll
  for (int i = 0; i < 4; ++i){
    float* dst = lt + (((n*9+g)*128 + o0 + i) * 1024) + l0;
    float4 s0 = {acc[i][0], acc[i][1], acc[i][2], acc[i][3]};
    float4 s1 = {acc[i][4], acc[i][5], acc[i][6], acc[i][7]};
    ((float4*)dst)[0] = s0;
    ((float4*)dst)[1] = s1;
  }
}

// ================= K_STATS_FAST: two-pass BN stats over stored lt =================
// arithmetic identical to the r1 (passing) k_stats: f64 sums, same per-thread order,
// same 256-wide tree, f32 c and c*c in pass 2.
__global__ __launch_bounds__(256) void k_stats_fast(const float* __restrict__ lt,
        float* __restrict__ mv){
  #pragma clang fp contract(off)
  __shared__ double red[256];
  int g = blockIdx.x >> 7, o = blockIdx.x & 127, t = threadIdx.x;
  double s1 = 0.0;
  for (int n = 0; n < 32; ++n){
    const float* p = lt + ((size_t)((n*9+g)*128 + o)) * 1024;
    for (int j = 0; j < 4; ++j) s1 += (double)p[t + j*256];
  }
  red[t] = s1; __syncthreads();
  for (int k = 128; k > 0; k >>= 1){ if (t < k) red[t] += red[t+k]; __syncthreads(); }
  float mean = (float)(red[0] / 32768.0);
  __syncthreads();
  double s2 = 0.0;
  for (int n = 0; n < 32; ++n){
    const float* p = lt + ((size_t)((n*9+g)*128 + o)) * 1024;
    for (int j = 0; j < 4; ++j){
      float tv = p[t + j*256];
      float c = tv - mean;
      float sq = c * c;
      s2 += (double)sq;
    }
  }
  red[t] = s2; __syncthreads();
  for (int k = 128; k > 0; k >>= 1){ if (t < k) red[t] += red[t+k]; __syncthreads(); }
  if (t == 0){
    float var = (float)(red[0] / 32768.0);
    float den = __builtin_sqrtf(var + 1e-5f);
    mv[(g*128+o)*2]   = mean;
    mv[(g*128+o)*2+1] = den;
  }
}

// ================= K_OUT_FAST: decisions + exact f32 recombination (reads lt) ========
__global__ __launch_bounds__(256) void k_out_fast(const float* __restrict__ lt,
        const float* __restrict__ mv, const uint32_t* __restrict__ keys,
        const float* __restrict__ gamma, const float* __restrict__ beta,
        float* __restrict__ out){
  #pragma clang fp contract(off)
  __shared__ float    mvL[18];
  __shared__ uint32_t kL[18];
  int bi = blockIdx.x;                  // 4096 = 8 b * 128 o * 4 lc
  int lc = bi & 3, o = (bi >> 2) & 127, b = bi >> 9;
  int t = threadIdx.x;
  if (t < 18){ mvL[t] = mv[((t>>1)*128 + o)*2 + (t&1)]; kL[t] = keys[t]; }
  __syncthreads();
  int l = lc*256 + t;
  float gma = gamma[o], bta = beta[o];
  float S[4] = {0.0f, 0.0f, 0.0f, 0.0f};
  for (int g = 0; g < 9; ++g){
    float rnd[4];
#if PRNG_PARTITIONABLE
    #pragma unroll
    for (int a = 0; a < 4; ++a){
      uint32_t m = (uint32_t)((a*8 + b)*131072 + o*1024 + l);
      uint32_t x0 = 0u, x1 = m;
      threefry2x32(kL[2*g], kL[2*g+1], x0, x1);
      rnd[a] = bits_to_unit(x0 ^ x1);
    }
#else
    #pragma unroll
    for (int a01 = 0; a01 < 2; ++a01){
      uint32_t m = (uint32_t)((a01*8 + b)*131072 + o*1024 + l);
      uint32_t x0 = m, x1 = m + 2097152u;
      threefry2x32(kL[2*g], kL[2*g+1], x0, x1);
      rnd[a01]     = bits_to_unit(x0);
      rnd[a01 + 2] = bits_to_unit(x1);
    }
#endif
    float mean = mvL[2*g], den = mvL[2*g+1];
    #pragma unroll
    for (int a = 0; a < 4; ++a){
      int n = a*8 + b;
      float tv = lt[((size_t)((n*9+g)*128 + o)) * 1024 + l];
      float normed = (tv - mean) / den * gma + bta;
      float th = xla_tanh_f32(4.0f * normed);
      float dec = (th > rnd[a]) ? 1.0f : -1.0f;
      if (normed == 0.0f) dec = 0.0f;
      float cc  = __builtin_fminf(__builtin_fmaxf(normed, -1.0f), 1.0f);
      float fwd = cc + (dec - cc);
      float pre = fwd / 9.0f;
      S[a] = S[a] + pre;
    }
  }
  float z = S[0] * 0.5f;
  z = z + S[1] * 0.25f;
  z = z + S[2] * 0.125f;
  z = z + S[3] * 0.0625f;
  out[(b*128 + o)*1024 + l] = z;
}

// ================= fallback (r1, slow but verified) =================
__global__ __launch_bounds__(256) void k_stats_slow(const float* __restrict__ qw,
        const unsigned long long* __restrict__ sgn, const unsigned long long* __restrict__ dimw,
        float* __restrict__ mv){
  #pragma clang fp contract(off)
  __shared__ double red[256];
  int g = blockIdx.x >> 7, o = blockIdx.x & 127, t = threadIdx.x;
  float wr[64];
  #pragma unroll
  for (int k = 0; k < 64; ++k) wr[k] = qw[(g*128 + o)*64 + k];
  double s1 = 0.0;
  for (int n = 0; n < 32; ++n){
    const unsigned long long* sp = sgn  + (n*9 + g)*1024;
    const unsigned long long* dp = dimw + (n*9 + g)*1024;
    for (int j = 0; j < 4; ++j){
      int l = t + j*256;
      float tv = dot64(sp[l], dp[l], wr);
      s1 += (double)tv;
    }
  }
  red[t] = s1; __syncthreads();
  for (int k = 128; k > 0; k >>= 1){ if (t < k) red[t] += red[t+k]; __syncthreads(); }
  float mean = (float)(red[0] / 32768.0);
  __syncthreads();
  double s2 = 0.0;
  for (int n = 0; n < 32; ++n){
    const unsigned long long* sp = sgn  + (n*9 + g)*1024;
    const unsigned long long* dp = dimw + (n*9 + g)*1024;
    for (int j = 0; j < 4; ++j){
      int l = t + j*256;
      float tv = dot64(sp[l], dp[l], wr);
      float c = tv - mean;
      float sq = c * c;
      s2 += (double)sq;
    }
  }
  red[t] = s2; __syncthreads();
  for (int k = 128; k > 0; k >>= 1){ if (t < k) red[t] += red[t+k]; __syncthreads(); }
  if (t == 0){
    float var = (float)(red[0] / 32768.0);
    float den = __builtin_sqrtf(var + 1e-5f);
    mv[(g*128+o)*2]   = mean;
    mv[(g*128+o)*2+1] = den;
  }
}

__global__ __launch_bounds__(256) void k_out_slow(const float* __restrict__ qw,
        const unsigned long long* __restrict__ sgn, const unsigned long long* __restrict__ dimw,
        const float* __restrict__ mv, const uint32_t* __restrict__ keys,
        const float* __restrict__ gamma, const float* __restrict__ beta,
        float* __restrict__ out){
  #pragma clang fp contract(off)
  __shared__ float    wv[576];
  __shared__ float    mvL[18];
  __shared__ uint32_t kL[18];
  int bi = blockIdx.x;
  int lc = bi & 3, o = (bi >> 2) & 127, b = bi >> 9;
  int t = threadIdx.x;
  for (int j = t; j < 576; j += 256) wv[j] = qw[((j >> 6)*128 + o)*64 + (j & 63)];
  if (t < 18){ mvL[t] = mv[((t>>1)*128 + o)*2 + (t&1)]; kL[t] = keys[t]; }
  __syncthreads();
  int l = lc*256 + t;
  float gma = gamma[o], bta = beta[o];
  float S[4] = {0.0f, 0.0f, 0.0f, 0.0f};
  for (int g = 0; g < 9; ++g){
    float rnd[4];
#if PRNG_PARTITIONABLE
    #pragma unroll
    for (int a = 0; a < 4; ++a){
      uint32_t m = (uint32_t)((a*8 + b)*131072 + o*1024 + l);
      uint32_t x0 = 0u, x1 = m;
      threefry2x32(kL[2*g], kL[2*g+1], x0, x1);
      rnd[a] = bits_to_unit(x0 ^ x1);
    }
#else
    #pragma unroll
    for (int a01 = 0; a01 < 2; ++a01){
      uint32_t m = (uint32_t)((a01*8 + b)*131072 + o*1024 + l);
      uint32_t x0 = m, x1 = m + 2097152u;
      threefry2x32(kL[2*g], kL[2*g+1], x0, x1);
      rnd[a01]     = bits_to_unit(x0);
      rnd[a01 + 2] = bits_to_unit(x1);
    }
#endif
    float mean = mvL[2*g], den = mvL[2*g+1];
    float wr[64];
    #pragma unroll
    for (int k = 0; k < 64; ++k) wr[k] = wv[g*64 + k];
    #pragma unroll
    for (int a = 0; a < 4; ++a){
      int n = a*8 + b;
      float tv = dot64(sgn[(n*9+g)*1024 + l], dimw[(n*9+g)*1024 + l], wr);
      float normed = (tv - mean) / den * gma + bta;
      float th = xla_tanh_f32(4.0f * normed);
      float dec = (th > rnd[a]) ? 1.0f : -1.0f;
      if (normed == 0.0f) dec = 0.0f;
      float cc  = __builtin_fminf(__builtin_fmaxf(normed, -1.0f), 1.0f);
      float fwd = cc + (dec - cc);
      float pre = fwd / 9.0f;
      S[a] = S[a] + pre;
    }
  }
  float z = S[0] * 0.5f;
  z = z + S[1] * 0.25f;
  z = z + S[2] * 0.125f;
  z = z + S[3] * 0.0625f;
  out[(b*128 + o)*1024 + l] = z;
}

extern "C" void kernel_launch(void* const* d_in, const int* in_sizes, int n_in,
                              void* d_out, int out_size, void* d_ws, size_t ws_size,
                              hipStream_t stream){
  (void)in_sizes; (void)n_in; (void)out_size;
  const float* inp   = (const float*)d_in[0];
  const float* wgt   = (const float*)d_in[1];
  const float* gamma = (const float*)d_in[2];
  const float* beta  = (const float*)d_in[3];
  float* out = (float*)d_out;
  char* ws = (char*)d_ws;
  float*              qw   = (float*)(ws + QW_OFF);
  float*              qwT  = (float*)(ws + QWT_OFF);
  unsigned long long* sgn  = (unsigned long long*)(ws + SGN_OFF);
  unsigned long long* dimw = (unsigned long long*)(ws + DIM_OFF);
  uint32_t*           keys = (uint32_t*)(ws + KEYS_OFF);
  float*              mv   = (float*)(ws + MV_OFF);
  float*              lt   = (float*)(ws + LT_OFF);

  hipLaunchKernelGGL(k_weights, dim3(128), dim3(64),  0, stream, wgt, qw, qwT, keys);
  hipLaunchKernelGGL(k_stream,  dim3(32),  dim3(256), 0, stream, inp, sgn, dimw);
  if (ws_size >= (size_t)WS_NEEDED_FAST){
    hipLaunchKernelGGL(k_gemm,       dim3(16, 9, 32), dim3(256), 0, stream, qwT, sgn, dimw, lt);
    hipLaunchKernelGGL(k_stats_fast, dim3(1152),      dim3(256), 0, stream, lt, mv);
    hipLaunchKernelGGL(k_out_fast,   dim3(4096),      dim3(256), 0, stream, lt, mv, keys,
                       gamma, beta, out);
  } else {
    hipLaunchKernelGGL(k_stats_slow, dim3(1152), dim3(256), 0, stream, qw, sgn, dimw, mv);
    hipLaunchKernelGGL(k_out_slow,   dim3(4096), dim3(256), 0, stream, qw, sgn, dimw, mv, keys,
                       gamma, beta, out);
  }
}

// Round 3
// 331.259 us; speedup vs baseline: 6.7192x; 3.3310x over previous
//
#include <hip/hip_runtime.h>
#include <stdint.h>

// ---- PRNG mode: 1 = jax_threefry_partitionable (default in jax >= 0.5)
#ifndef PRNG_PARTITIONABLE
#define PRNG_PARTITIONABLE 1
#endif

#define ONE_M_U 0.99999994039535522461f   // 1 - 2^-24 (0x3F7FFFFF)

// ---------------- threefry2x32 (exact JAX rounds) ----------------
__device__ __forceinline__ void tf_4a(uint32_t& x0, uint32_t& x1){
  x0 += x1; x1 = (x1<<13)|(x1>>19); x1 ^= x0;
  x0 += x1; x1 = (x1<<15)|(x1>>17); x1 ^= x0;
  x0 += x1; x1 = (x1<<26)|(x1>>6);  x1 ^= x0;
  x0 += x1; x1 = (x1<<6) |(x1>>26); x1 ^= x0;
}
__device__ __forceinline__ void tf_4b(uint32_t& x0, uint32_t& x1){
  x0 += x1; x1 = (x1<<17)|(x1>>15); x1 ^= x0;
  x0 += x1; x1 = (x1<<29)|(x1>>3);  x1 ^= x0;
  x0 += x1; x1 = (x1<<16)|(x1>>16); x1 ^= x0;
  x0 += x1; x1 = (x1<<24)|(x1>>8);  x1 ^= x0;
}
__device__ __forceinline__ void threefry2x32(uint32_t k0, uint32_t k1, uint32_t& x0, uint32_t& x1){
  uint32_t k2 = k0 ^ k1 ^ 0x1BD11BDAu;
  x0 += k0; x1 += k1;
  tf_4a(x0,x1); x0 += k1; x1 += k2 + 1u;
  tf_4b(x0,x1); x0 += k2; x1 += k0 + 2u;
  tf_4a(x0,x1); x0 += k0; x1 += k1 + 3u;
  tf_4b(x0,x1); x0 += k1; x1 += k2 + 4u;
  tf_4a(x0,x1); x0 += k2; x1 += k0 + 5u;
}

__device__ __forceinline__ float bits_to_unit(uint32_t b){
  #pragma clang fp contract(off)
  float f = __uint_as_float((b >> 9) | 0x3f800000u) - 1.0f;
  float r = f * 2.0f + (-1.0f);
  return __builtin_fmaxf(-1.0f, r);
}

// XLA elemental_ir_emitter EmitTanh f32 (unfused mul/add)
__device__ __forceinline__ float xla_tanh_f32(float x){
  #pragma clang fp contract(off)
  float ax = __builtin_fabsf(x);
  float xc = __builtin_fminf(__builtin_fmaxf(x, -9.0f), 9.0f);
  float x2 = xc * xc;
  float nm = -2.76076847742355e-16f;
  nm = x2 * nm + 2.00018790482477e-13f;
  nm = x2 * nm + -8.60467152213735e-11f;
  nm = x2 * nm + 5.12229709037114e-08f;
  nm = x2 * nm + 1.48572235717979e-05f;
  nm = x2 * nm + 6.37261928875436e-04f;
  nm = x2 * nm + 4.89352455891786e-03f;
  nm = xc * nm;
  float dn = 1.19825839466702e-06f;
  dn = x2 * dn + 1.18534705686654e-04f;
  dn = x2 * dn + 2.26843463243900e-03f;
  dn = x2 * dn + 4.89352518554385e-03f;
  float res = nm / dn;
  return (ax < 0.0004f) ? x : res;
}

// k-ascending fma chain (fallback path only)
__device__ __forceinline__ float dot64(unsigned long long sw, unsigned long long dw,
                                       const float* w){
  float acc = 0.0f;
  #pragma unroll
  for (int k = 0; k < 64; ++k){
    float mag = ((dw >> k) & 1ull) ? ONE_M_U : 1.0f;
    float p   = ((sw >> k) & 1ull) ? mag : -mag;
    acc = __builtin_fmaf(p, w[k], acc);
  }
  return acc;
}

// -------- workspace layout (bytes) --------
#define QW_OFF   0u           // float[9][128][64]   ([g][o][k])
#define QWT_OFF  294912u      // float[9][64][128]   ([g][k][o])
#define SGN_OFF  589824u      // u64[32][9][1024]
#define DIM_OFF  2949120u     // u64[32][9][1024]
#define KEYS_OFF 5308416u     // u32[18]
#define MV_OFF   5308544u     // float[9*128][2]
#define LT_OFF   5318656u     // float[32][9][128][1024]  (fast path only)
#define LT_BYTES 150994944u
#define WS_NEEDED_FAST (LT_OFF + LT_BYTES)

// ================= K1: weight standardize + quantize + PRNG keys =================
__global__ __launch_bounds__(64) void k_weights(const float* __restrict__ W,
        float* __restrict__ qw, float* __restrict__ qwT, uint32_t* __restrict__ keys){
  #pragma clang fp contract(off)
  __shared__ float  bwL[576];
  __shared__ double red[64];
  int o = blockIdx.x, t = threadIdx.x;
  double s = 0.0;
  for (int j = t; j < 576; j += 64) s += (double)W[o*576 + j];
  red[t] = s; __syncthreads();
  for (int k = 32; k > 0; k >>= 1){ if (t < k) red[t] += red[t+k]; __syncthreads(); }
  float mean1 = (float)(red[0] / 576.0);
  __syncthreads();
  for (int j = t; j < 576; j += 64) bwL[j] = W[o*576 + j] - mean1;
  __syncthreads();
  s = 0.0;
  for (int j = t; j < 576; j += 64) s += (double)bwL[j];
  red[t] = s; __syncthreads();
  for (int k = 32; k > 0; k >>= 1){ if (t < k) red[t] += red[t+k]; __syncthreads(); }
  float mean2 = (float)(red[0] / 576.0);
  __syncthreads();
  s = 0.0;
  for (int j = t; j < 576; j += 64){ float c = bwL[j] - mean2; float sq = c * c; s += (double)sq; }
  red[t] = s; __syncthreads();
  for (int k = 32; k > 0; k >>= 1){ if (t < k) red[t] += red[t+k]; __syncthreads(); }
  float varf = (float)(red[0] / 575.0);
  float stdv = __builtin_sqrtf(varf);
  __syncthreads();
  for (int j = t; j < 576; j += 64){
    float b2 = bwL[j] / stdv;
    float c  = __builtin_fminf(__builtin_fmaxf(b2, -1.0f), 1.0f);
    float q  = __builtin_rintf(c * 7.0f) / 7.0f;
    float fwd = c + (q - c);
    int g = j >> 6, k = j & 63;
    qw [(g*128 + o)*64 + k] = fwd;
    qwT[(g*64  + k)*128 + o] = fwd;
  }
  if (o == 0 && t == 0){
#if PRNG_PARTITIONABLE
    for (int g = 0; g < 9; ++g){
      uint32_t x0 = 0u, x1 = (uint32_t)g;
      threefry2x32(0u, 42u, x0, x1);
      keys[2*g] = x0; keys[2*g+1] = x1;
    }
#else
    uint32_t outv[18];
    for (int i = 0; i < 9; ++i){
      uint32_t x0 = (uint32_t)i, x1 = (uint32_t)(9 + i);
      threefry2x32(0u, 42u, x0, x1);
      outv[i] = x0; outv[9+i] = x1;
    }
    for (int j = 0; j < 18; ++j) keys[j] = outv[j];
#endif
  }
}

// ================= K2: unfold + clip + residual sign planes =================
// One thread per (b, l, g): 8 u64 bitmasks in NAMED registers (no dynamic array
// indexing -> no scratch spill, the r2 killer). grid (32, 9). c,kp,di,dj are
// wave-uniform (g uniform per block, i compile-time) -> SALU.
// f32 op sequence per plane identical to the verified r1 kernel.
__global__ __launch_bounds__(256) void k_stream(const float* __restrict__ X,
        unsigned long long* __restrict__ sgn, unsigned long long* __restrict__ dimw){
  #pragma clang fp contract(off)
  int g = blockIdx.y;
  int tid = blockIdx.x * 256 + threadIdx.x;   // 0..8191
  int b = tid >> 10, l = tid & 1023;
  int h = l >> 5, w = l & 31;
  unsigned long long sw0=0ull, sw1=0ull, sw2=0ull, sw3=0ull;
  unsigned long long dw0=0ull, dw1=0ull, dw2=0ull, dw3=0ull;
  const float* Xb = X + b*64*1024;
  int ck0 = g*64;
  #pragma unroll
  for (int i = 0; i < 64; ++i){
    int ck = ck0 + i;
    int c = ck / 9, kp = ck % 9;          // wave-uniform -> scalar ops
    int di = kp / 3 - 1, dj = kp % 3 - 1; // wave-uniform
    int hh = h + di, ww = w + dj;
    float v = 0.0f;
    if (hh >= 0 && hh < 32 && ww >= 0 && ww < 32)
      v = Xb[(c*32 + hh)*32 + ww];
    float x = __builtin_fminf(__builtin_fmaxf(v, -1.0f), 1.0f);
    float r = x;
    // a = 0
    {
      float sv = (r >= 0.0f) ? 1.0f : -1.0f;
      float d  = sv - x;
      float p  = x + d;
      if (sv > 0.0f) sw0 |= (1ull << i);
      if (__builtin_fabsf(p) < 1.0f) dw0 |= (1ull << i);
      r = r - sv * 0.5f;
    }
    // a = 1
    {
      float sv = (r >= 0.0f) ? 1.0f : -1.0f;
      float d  = sv - x;
      float p  = x + d;
      if (sv > 0.0f) sw1 |= (1ull << i);
      if (__builtin_fabsf(p) < 1.0f) dw1 |= (1ull << i);
      r = r - sv * 0.25f;
    }
    // a = 2
    {
      float sv = (r >= 0.0f) ? 1.0f : -1.0f;
      float d  = sv - x;
      float p  = x + d;
      if (sv > 0.0f) sw2 |= (1ull << i);
      if (__builtin_fabsf(p) < 1.0f) dw2 |= (1ull << i);
      r = r - sv * 0.125f;
    }
    // a = 3
    {
      float sv = (r >= 0.0f) ? 1.0f : -1.0f;
      float d  = sv - x;
      float p  = x + d;
      if (sv > 0.0f) sw3 |= (1ull << i);
      if (__builtin_fabsf(p) < 1.0f) dw3 |= (1ull << i);
      r = r - sv * 0.0625f;
    }
  }
  sgn [((0*8+b)*9 + g)*1024 + l] = sw0;
  sgn [((1*8+b)*9 + g)*1024 + l] = sw1;
  sgn [((2*8+b)*9 + g)*1024 + l] = sw2;
  sgn [((3*8+b)*9 + g)*1024 + l] = sw3;
  dimw[((0*8+b)*9 + g)*1024 + l] = dw0;
  dimw[((1*8+b)*9 + g)*1024 + l] = dw1;
  dimw[((2*8+b)*9 + g)*1024 + l] = dw2;
  dimw[((3*8+b)*9 + g)*1024 + l] = dw3;
}

// ================= K_GEMM: decode-once register-blocked GEMM -> lt =================
__global__ __launch_bounds__(256) void k_gemm(const float* __restrict__ qwT,
        const unsigned long long* __restrict__ sgn, const unsigned long long* __restrict__ dimw,
        float* __restrict__ lt){
  __shared__ float wT[64*128];   // [k][o]
  __shared__ float pL[64*64];    // [k][lc]
  int lchunk = blockIdx.x, g = blockIdx.y, n = blockIdx.z;
  int t = threadIdx.x;
  for (int j = t; j < 8192; j += 256) wT[j] = qwT[g*8192 + j];  // j = k*128+o, coalesced
  {
    int lc = t & 63, kq = t >> 6;
    unsigned long long sw = sgn [(n*9+g)*1024 + lchunk*64 + lc];
    unsigned long long dw = dimw[(n*9+g)*1024 + lchunk*64 + lc];
    #pragma unroll
    for (int kk = 0; kk < 16; ++kk){
      int k = kq*16 + kk;
      float mag = ((dw >> k) & 1ull) ? ONE_M_U : 1.0f;
      float p   = ((sw >> k) & 1ull) ? mag : -mag;
      pL[k*64 + lc] = p;
    }
  }
  __syncthreads();
  int otile = t & 31, ltile = t >> 5;
  const float4* wT4 = (const float4*)wT;
  const float4* pL4 = (const float4*)pL;
  float acc[4][8];
  #pragma unroll
  for (int i = 0; i < 4; ++i)
    #pragma unroll
    for (int j = 0; j < 8; ++j) acc[i][j] = 0.0f;
  #pragma unroll 8
  for (int k = 0; k < 64; ++k){
    float4 wv = wT4[k*32 + otile];
    float4 pa = pL4[k*16 + ltile*2];
    float4 pb = pL4[k*16 + ltile*2 + 1];
    float wr[4] = {wv.x, wv.y, wv.z, wv.w};
    float pr[8] = {pa.x, pa.y, pa.z, pa.w, pb.x, pb.y, pb.z, pb.w};
    #pragma unroll
    for (int i = 0; i < 4; ++i)
      #pragma unroll
      for (int j = 0; j < 8; ++j)
        acc[i][j] = __builtin_fmaf(pr[j], wr[i], acc[i][j]);
  }
  int o0 = otile*4, l0 = lchunk*64 + ltile*8;
  #pragma unroll
  for (int i = 0; i < 4; ++i){
    float* dst = lt + (((n*9+g)*128 + o0 + i) * 1024) + l0;
    float4 s0 = {acc[i][0], acc[i][1], acc[i][2], acc[i][3]};
    float4 s1 = {acc[i][4], acc[i][5], acc[i][6], acc[i][7]};
    ((float4*)dst)[0] = s0;
    ((float4*)dst)[1] = s1;
  }
}

// ================= K_STATS_FAST: two-pass BN stats over stored lt =================
__global__ __launch_bounds__(256) void k_stats_fast(const float* __restrict__ lt,
        float* __restrict__ mv){
  #pragma clang fp contract(off)
  __shared__ double red[256];
  int g = blockIdx.x >> 7, o = blockIdx.x & 127, t = threadIdx.x;
  double s1 = 0.0;
  for (int n = 0; n < 32; ++n){
    const float* p = lt + ((size_t)((n*9+g)*128 + o)) * 1024;
    for (int j = 0; j < 4; ++j) s1 += (double)p[t + j*256];
  }
  red[t] = s1; __syncthreads();
  for (int k = 128; k > 0; k >>= 1){ if (t < k) red[t] += red[t+k]; __syncthreads(); }
  float mean = (float)(red[0] / 32768.0);
  __syncthreads();
  double s2 = 0.0;
  for (int n = 0; n < 32; ++n){
    const float* p = lt + ((size_t)((n*9+g)*128 + o)) * 1024;
    for (int j = 0; j < 4; ++j){
      float tv = p[t + j*256];
      float c = tv - mean;
      float sq = c * c;
      s2 += (double)sq;
    }
  }
  red[t] = s2; __syncthreads();
  for (int k = 128; k > 0; k >>= 1){ if (t < k) red[t] += red[t+k]; __syncthreads(); }
  if (t == 0){
    float var = (float)(red[0] / 32768.0);
    float den = __builtin_sqrtf(var + 1e-5f);
    mv[(g*128+o)*2]   = mean;
    mv[(g*128+o)*2+1] = den;
  }
}

// ================= K_OUT_FAST: decisions + exact f32 recombination (reads lt) ========
__global__ __launch_bounds__(256) void k_out_fast(const float* __restrict__ lt,
        const float* __restrict__ mv, const uint32_t* __restrict__ keys,
        const float* __restrict__ gamma, const float* __restrict__ beta,
        float* __restrict__ out){
  #pragma clang fp contract(off)
  __shared__ float    mvL[18];
  __shared__ uint32_t kL[18];
  int bi = blockIdx.x;                  // 4096 = 8 b * 128 o * 4 lc
  int lc = bi & 3, o = (bi >> 2) & 127, b = bi >> 9;
  int t = threadIdx.x;
  if (t < 18){ mvL[t] = mv[((t>>1)*128 + o)*2 + (t&1)]; kL[t] = keys[t]; }
  __syncthreads();
  int l = lc*256 + t;
  float gma = gamma[o], bta = beta[o];
  float S[4] = {0.0f, 0.0f, 0.0f, 0.0f};
  for (int g = 0; g < 9; ++g){
    float rnd[4];
#if PRNG_PARTITIONABLE
    #pragma unroll
    for (int a = 0; a < 4; ++a){
      uint32_t m = (uint32_t)((a*8 + b)*131072 + o*1024 + l);
      uint32_t x0 = 0u, x1 = m;
      threefry2x32(kL[2*g], kL[2*g+1], x0, x1);
      rnd[a] = bits_to_unit(x0 ^ x1);
    }
#else
    #pragma unroll
    for (int a01 = 0; a01 < 2; ++a01){
      uint32_t m = (uint32_t)((a01*8 + b)*131072 + o*1024 + l);
      uint32_t x0 = m, x1 = m + 2097152u;
      threefry2x32(kL[2*g], kL[2*g+1], x0, x1);
      rnd[a01]     = bits_to_unit(x0);
      rnd[a01 + 2] = bits_to_unit(x1);
    }
#endif
    float mean = mvL[2*g], den = mvL[2*g+1];
    #pragma unroll
    for (int a = 0; a < 4; ++a){
      int n = a*8 + b;
      float tv = lt[((size_t)((n*9+g)*128 + o)) * 1024 + l];
      float normed = (tv - mean) / den * gma + bta;
      float th = xla_tanh_f32(4.0f * normed);
      float dec = (th > rnd[a]) ? 1.0f : -1.0f;
      if (normed == 0.0f) dec = 0.0f;
      float cc  = __builtin_fminf(__builtin_fmaxf(normed, -1.0f), 1.0f);
      float fwd = cc + (dec - cc);
      float pre = fwd / 9.0f;
      S[a] = S[a] + pre;
    }
  }
  float z = S[0] * 0.5f;
  z = z + S[1] * 0.25f;
  z = z + S[2] * 0.125f;
  z = z + S[3] * 0.0625f;
  out[(b*128 + o)*1024 + l] = z;
}

// ================= fallback (r1, slow but verified) =================
__global__ __launch_bounds__(256) void k_stats_slow(const float* __restrict__ qw,
        const unsigned long long* __restrict__ sgn, const unsigned long long* __restrict__ dimw,
        float* __restrict__ mv){
  #pragma clang fp contract(off)
  __shared__ double red[256];
  int g = blockIdx.x >> 7, o = blockIdx.x & 127, t = threadIdx.x;
  float wr[64];
  #pragma unroll
  for (int k = 0; k < 64; ++k) wr[k] = qw[(g*128 + o)*64 + k];
  double s1 = 0.0;
  for (int n = 0; n < 32; ++n){
    const unsigned long long* sp = sgn  + (n*9 + g)*1024;
    const unsigned long long* dp = dimw + (n*9 + g)*1024;
    for (int j = 0; j < 4; ++j){
      int l = t + j*256;
      float tv = dot64(sp[l], dp[l], wr);
      s1 += (double)tv;
    }
  }
  red[t] = s1; __syncthreads();
  for (int k = 128; k > 0; k >>= 1){ if (t < k) red[t] += red[t+k]; __syncthreads(); }
  float mean = (float)(red[0] / 32768.0);
  __syncthreads();
  double s2 = 0.0;
  for (int n = 0; n < 32; ++n){
    const unsigned long long* sp = sgn  + (n*9 + g)*1024;
    const unsigned long long* dp = dimw + (n*9 + g)*1024;
    for (int j = 0; j < 4; ++j){
      int l = t + j*256;
      float tv = dot64(sp[l], dp[l], wr);
      float c = tv - mean;
      float sq = c * c;
      s2 += (double)sq;
    }
  }
  red[t] = s2; __syncthreads();
  for (int k = 128; k > 0; k >>= 1){ if (t < k) red[t] += red[t+k]; __syncthreads(); }
  if (t == 0){
    float var = (float)(red[0] / 32768.0);
    float den = __builtin_sqrtf(var + 1e-5f);
    mv[(g*128+o)*2]   = mean;
    mv[(g*128+o)*2+1] = den;
  }
}

__global__ __launch_bounds__(256) void k_out_slow(const float* __restrict__ qw,
        const unsigned long long* __restrict__ sgn, const unsigned long long* __restrict__ dimw,
        const float* __restrict__ mv, const uint32_t* __restrict__ keys,
        const float* __restrict__ gamma, const float* __restrict__ beta,
        float* __restrict__ out){
  #pragma clang fp contract(off)
  __shared__ float    wv[576];
  __shared__ float    mvL[18];
  __shared__ uint32_t kL[18];
  int bi = blockIdx.x;
  int lc = bi & 3, o = (bi >> 2) & 127, b = bi >> 9;
  int t = threadIdx.x;
  for (int j = t; j < 576; j += 256) wv[j] = qw[((j >> 6)*128 + o)*64 + (j & 63)];
  if (t < 18){ mvL[t] = mv[((t>>1)*128 + o)*2 + (t&1)]; kL[t] = keys[t]; }
  __syncthreads();
  int l = lc*256 + t;
  float gma = gamma[o], bta = beta[o];
  float S[4] = {0.0f, 0.0f, 0.0f, 0.0f};
  for (int g = 0; g < 9; ++g){
    float rnd[4];
#if PRNG_PARTITIONABLE
    #pragma unroll
    for (int a = 0; a < 4; ++a){
      uint32_t m = (uint32_t)((a*8 + b)*131072 + o*1024 + l);
      uint32_t x0 = 0u, x1 = m;
      threefry2x32(kL[2*g], kL[2*g+1], x0, x1);
      rnd[a] = bits_to_unit(x0 ^ x1);
    }
#else
    #pragma unroll
    for (int a01 = 0; a01 < 2; ++a01){
      uint32_t m = (uint32_t)((a01*8 + b)*131072 + o*1024 + l);
      uint32_t x0 = m, x1 = m + 2097152u;
      threefry2x32(kL[2*g], kL[2*g+1], x0, x1);
      rnd[a01]     = bits_to_unit(x0);
      rnd[a01 + 2] = bits_to_unit(x1);
    }
#endif
    float mean = mvL[2*g], den = mvL[2*g+1];
    float wr[64];
    #pragma unroll
    for (int k = 0; k < 64; ++k) wr[k] = wv[g*64 + k];
    #pragma unroll
    for (int a = 0; a < 4; ++a){
      int n = a*8 + b;
      float tv = dot64(sgn[(n*9+g)*1024 + l], dimw[(n*9+g)*1024 + l], wr);
      float normed = (tv - mean) / den * gma + bta;
      float th = xla_tanh_f32(4.0f * normed);
      float dec = (th > rnd[a]) ? 1.0f : -1.0f;
      if (normed == 0.0f) dec = 0.0f;
      float cc  = __builtin_fminf(__builtin_fmaxf(normed, -1.0f), 1.0f);
      float fwd = cc + (dec - cc);
      float pre = fwd / 9.0f;
      S[a] = S[a] + pre;
    }
  }
  float z = S[0] * 0.5f;
  z = z + S[1] * 0.25f;
  z = z + S[2] * 0.125f;
  z = z + S[3] * 0.0625f;
  out[(b*128 + o)*1024 + l] = z;
}

extern "C" void kernel_launch(void* const* d_in, const int* in_sizes, int n_in,
                              void* d_out, int out_size, void* d_ws, size_t ws_size,
                              hipStream_t stream){
  (void)in_sizes; (void)n_in; (void)out_size;
  const float* inp   = (const float*)d_in[0];
  const float* wgt   = (const float*)d_in[1];
  const float* gamma = (const float*)d_in[2];
  const float* beta  = (const float*)d_in[3];
  float* out = (float*)d_out;
  char* ws = (char*)d_ws;
  float*              qw   = (float*)(ws + QW_OFF);
  float*              qwT  = (float*)(ws + QWT_OFF);
  unsigned long long* sgn  = (unsigned long long*)(ws + SGN_OFF);
  unsigned long long* dimw = (unsigned long long*)(ws + DIM_OFF);
  uint32_t*           keys = (uint32_t*)(ws + KEYS_OFF);
  float*              mv   = (float*)(ws + MV_OFF);
  float*              lt   = (float*)(ws + LT_OFF);

  hipLaunchKernelGGL(k_weights, dim3(128),    dim3(64),  0, stream, wgt, qw, qwT, keys);
  hipLaunchKernelGGL(k_stream,  dim3(32, 9),  dim3(256), 0, stream, inp, sgn, dimw);
  if (ws_size >= (size_t)WS_NEEDED_FAST){
    hipLaunchKernelGGL(k_gemm,       dim3(16, 9, 32), dim3(256), 0, stream, qwT, sgn, dimw, lt);
    hipLaunchKernelGGL(k_stats_fast, dim3(1152),      dim3(256), 0, stream, lt, mv);
    hipLaunchKernelGGL(k_out_fast,   dim3(4096),      dim3(256), 0, stream, lt, mv, keys,
                       gamma, beta, out);
  } else {
    hipLaunchKernelGGL(k_stats_slow, dim3(1152), dim3(256), 0, stream, qw, sgn, dimw, mv);
    hipLaunchKernelGGL(k_out_slow,   dim3(4096), dim3(256), 0, stream, qw, sgn, dimw, mv, keys,
                       gamma, beta, out);
  }
}

// Round 4
// 322.226 us; speedup vs baseline: 6.9076x; 1.0280x over previous
//
#include <hip/hip_runtime.h>
#include <stdint.h>

// ---- PRNG mode: 1 = jax_threefry_partitionable (default in jax >= 0.5)
#ifndef PRNG_PARTITIONABLE
#define PRNG_PARTITIONABLE 1
#endif

#define ONE_M_U 0.99999994039535522461f   // 1 - 2^-24 (0x3F7FFFFF)

// ---------------- threefry2x32 (exact JAX rounds) ----------------
__device__ __forceinline__ void tf_4a(uint32_t& x0, uint32_t& x1){
  x0 += x1; x1 = (x1<<13)|(x1>>19); x1 ^= x0;
  x0 += x1; x1 = (x1<<15)|(x1>>17); x1 ^= x0;
  x0 += x1; x1 = (x1<<26)|(x1>>6);  x1 ^= x0;
  x0 += x1; x1 = (x1<<6) |(x1>>26); x1 ^= x0;
}
__device__ __forceinline__ void tf_4b(uint32_t& x0, uint32_t& x1){
  x0 += x1; x1 = (x1<<17)|(x1>>15); x1 ^= x0;
  x0 += x1; x1 = (x1<<29)|(x1>>3);  x1 ^= x0;
  x0 += x1; x1 = (x1<<16)|(x1>>16); x1 ^= x0;
  x0 += x1; x1 = (x1<<24)|(x1>>8);  x1 ^= x0;
}
__device__ __forceinline__ void threefry2x32(uint32_t k0, uint32_t k1, uint32_t& x0, uint32_t& x1){
  uint32_t k2 = k0 ^ k1 ^ 0x1BD11BDAu;
  x0 += k0; x1 += k1;
  tf_4a(x0,x1); x0 += k1; x1 += k2 + 1u;
  tf_4b(x0,x1); x0 += k2; x1 += k0 + 2u;
  tf_4a(x0,x1); x0 += k0; x1 += k1 + 3u;
  tf_4b(x0,x1); x0 += k1; x1 += k2 + 4u;
  tf_4a(x0,x1); x0 += k2; x1 += k0 + 5u;
}

__device__ __forceinline__ float bits_to_unit(uint32_t b){
  #pragma clang fp contract(off)
  float f = __uint_as_float((b >> 9) | 0x3f800000u) - 1.0f;
  float r = f * 2.0f + (-1.0f);
  return __builtin_fmaxf(-1.0f, r);
}

// XLA elemental_ir_emitter EmitTanh f32 (unfused mul/add)
__device__ __forceinline__ float xla_tanh_f32(float x){
  #pragma clang fp contract(off)
  float ax = __builtin_fabsf(x);
  float xc = __builtin_fminf(__builtin_fmaxf(x, -9.0f), 9.0f);
  float x2 = xc * xc;
  float nm = -2.76076847742355e-16f;
  nm = x2 * nm + 2.00018790482477e-13f;
  nm = x2 * nm + -8.60467152213735e-11f;
  nm = x2 * nm + 5.12229709037114e-08f;
  nm = x2 * nm + 1.48572235717979e-05f;
  nm = x2 * nm + 6.37261928875436e-04f;
  nm = x2 * nm + 4.89352455891786e-03f;
  nm = xc * nm;
  float dn = 1.19825839466702e-06f;
  dn = x2 * dn + 1.18534705686654e-04f;
  dn = x2 * dn + 2.26843463243900e-03f;
  dn = x2 * dn + 4.89352518554385e-03f;
  float res = nm / dn;
  return (ax < 0.0004f) ? x : res;
}

// k-ascending fma chain (fallback path only)
__device__ __forceinline__ float dot64(unsigned long long sw, unsigned long long dw,
                                       const float* w){
  float acc = 0.0f;
  #pragma unroll
  for (int k = 0; k < 64; ++k){
    float mag = ((dw >> k) & 1ull) ? ONE_M_U : 1.0f;
    float p   = ((sw >> k) & 1ull) ? mag : -mag;
    acc = __builtin_fmaf(p, w[k], acc);
  }
  return acc;
}

// -------- workspace layout (bytes) --------
#define QW_OFF   0u           // float[9][128][64]   ([g][o][k])
#define SGN_OFF  294912u      // u64[32][9][1024]
#define DIM_OFF  2654208u     // u64[32][9][1024]
#define KEYS_OFF 5013504u     // u32[18]
#define MV_OFF   5013632u     // float[9*128][2]
#define LT_OFF   5023744u     // float[32][9][128][1024]  (fast path)
#define LT_BYTES 150994944u
#define PART_OFF (LT_OFF + LT_BYTES)       // double[9][128][256]
#define PART_BYTES 2359296u
#define WS_NEEDED_FAST (PART_OFF + PART_BYTES)

// ================= K1: weight standardize + quantize + PRNG keys =================
__global__ __launch_bounds__(64) void k_weights(const float* __restrict__ W,
        float* __restrict__ qw, uint32_t* __restrict__ keys){
  #pragma clang fp contract(off)
  __shared__ float  bwL[576];
  __shared__ double red[64];
  int o = blockIdx.x, t = threadIdx.x;
  double s = 0.0;
  for (int j = t; j < 576; j += 64) s += (double)W[o*576 + j];
  red[t] = s; __syncthreads();
  for (int k = 32; k > 0; k >>= 1){ if (t < k) red[t] += red[t+k]; __syncthreads(); }
  float mean1 = (float)(red[0] / 576.0);
  __syncthreads();
  for (int j = t; j < 576; j += 64) bwL[j] = W[o*576 + j] - mean1;
  __syncthreads();
  s = 0.0;
  for (int j = t; j < 576; j += 64) s += (double)bwL[j];
  red[t] = s; __syncthreads();
  for (int k = 32; k > 0; k >>= 1){ if (t < k) red[t] += red[t+k]; __syncthreads(); }
  float mean2 = (float)(red[0] / 576.0);
  __syncthreads();
  s = 0.0;
  for (int j = t; j < 576; j += 64){ float c = bwL[j] - mean2; float sq = c * c; s += (double)sq; }
  red[t] = s; __syncthreads();
  for (int k = 32; k > 0; k >>= 1){ if (t < k) red[t] += red[t+k]; __syncthreads(); }
  float varf = (float)(red[0] / 575.0);
  float stdv = __builtin_sqrtf(varf);
  __syncthreads();
  for (int j = t; j < 576; j += 64){
    float b2 = bwL[j] / stdv;
    float c  = __builtin_fminf(__builtin_fmaxf(b2, -1.0f), 1.0f);
    float q  = __builtin_rintf(c * 7.0f) / 7.0f;
    float fwd = c + (q - c);
    int g = j >> 6, k = j & 63;
    qw [(g*128 + o)*64 + k] = fwd;
  }
  if (o == 0 && t == 0){
#if PRNG_PARTITIONABLE
    for (int g = 0; g < 9; ++g){
      uint32_t x0 = 0u, x1 = (uint32_t)g;
      threefry2x32(0u, 42u, x0, x1);
      keys[2*g] = x0; keys[2*g+1] = x1;
    }
#else
    uint32_t outv[18];
    for (int i = 0; i < 9; ++i){
      uint32_t x0 = (uint32_t)i, x1 = (uint32_t)(9 + i);
      threefry2x32(0u, 42u, x0, x1);
      outv[i] = x0; outv[9+i] = x1;
    }
    for (int j = 0; j < 18; ++j) keys[j] = outv[j];
#endif
  }
}

// ================= K2: unfold + clip + residual sign planes =================
__global__ __launch_bounds__(256) void k_stream(const float* __restrict__ X,
        unsigned long long* __restrict__ sgn, unsigned long long* __restrict__ dimw){
  #pragma clang fp contract(off)
  int g = blockIdx.y;
  int tid = blockIdx.x * 256 + threadIdx.x;   // 0..8191
  int b = tid >> 10, l = tid & 1023;
  int h = l >> 5, w = l & 31;
  unsigned long long sw0=0ull, sw1=0ull, sw2=0ull, sw3=0ull;
  unsigned long long dw0=0ull, dw1=0ull, dw2=0ull, dw3=0ull;
  const float* Xb = X + b*64*1024;
  int ck0 = g*64;
  #pragma unroll
  for (int i = 0; i < 64; ++i){
    int ck = ck0 + i;
    int c = ck / 9, kp = ck % 9;          // wave-uniform -> scalar
    int di = kp / 3 - 1, dj = kp % 3 - 1;
    int hh = h + di, ww = w + dj;
    float v = 0.0f;
    if (hh >= 0 && hh < 32 && ww >= 0 && ww < 32)
      v = Xb[(c*32 + hh)*32 + ww];
    float x = __builtin_fminf(__builtin_fmaxf(v, -1.0f), 1.0f);
    float r = x;
    {
      float sv = (r >= 0.0f) ? 1.0f : -1.0f;
      float d  = sv - x; float p = x + d;
      if (sv > 0.0f) sw0 |= (1ull << i);
      if (__builtin_fabsf(p) < 1.0f) dw0 |= (1ull << i);
      r = r - sv * 0.5f;
    }
    {
      float sv = (r >= 0.0f) ? 1.0f : -1.0f;
      float d  = sv - x; float p = x + d;
      if (sv > 0.0f) sw1 |= (1ull << i);
      if (__builtin_fabsf(p) < 1.0f) dw1 |= (1ull << i);
      r = r - sv * 0.25f;
    }
    {
      float sv = (r >= 0.0f) ? 1.0f : -1.0f;
      float d  = sv - x; float p = x + d;
      if (sv > 0.0f) sw2 |= (1ull << i);
      if (__builtin_fabsf(p) < 1.0f) dw2 |= (1ull << i);
      r = r - sv * 0.125f;
    }
    {
      float sv = (r >= 0.0f) ? 1.0f : -1.0f;
      float d  = sv - x; float p = x + d;
      if (sv > 0.0f) sw3 |= (1ull << i);
      if (__builtin_fabsf(p) < 1.0f) dw3 |= (1ull << i);
      r = r - sv * 0.0625f;
    }
  }
  sgn [((0*8+b)*9 + g)*1024 + l] = sw0;
  sgn [((1*8+b)*9 + g)*1024 + l] = sw1;
  sgn [((2*8+b)*9 + g)*1024 + l] = sw2;
  sgn [((3*8+b)*9 + g)*1024 + l] = sw3;
  dimw[((0*8+b)*9 + g)*1024 + l] = dw0;
  dimw[((1*8+b)*9 + g)*1024 + l] = dw1;
  dimw[((2*8+b)*9 + g)*1024 + l] = dw2;
  dimw[((3*8+b)*9 + g)*1024 + l] = dw3;
}

// ================= K_GEMM v2: 8o x 8l tiles, decode-once, + f64 pass-1 partials ======
// block = one (n, g, 128-l chunk), covers all 128 o.
// thread: ot = t>>4 -> o in [ot*8, ot*8+8) (blocked); ltl = t&15 -> l = ltl + 16j (strided).
// LDS rows padded to 17 float4s: w-read lanes stride 8*17*4=544w (%32==8 over ot span: free);
// p-read lanes stride 17*4=68w (%32==4: 2-way, free).  k-ascending FMA chain preserved.
__global__ __launch_bounds__(256) void k_gemm(const float* __restrict__ qw,
        const unsigned long long* __restrict__ sgn, const unsigned long long* __restrict__ dimw,
        float* __restrict__ lt, double* __restrict__ part){
  __shared__ float4 wS[128*17];   // wS[o*17+kq] = w[g][o][4kq..4kq+3]
  __shared__ float4 pS[128*17];   // pS[l*17+kq] = p[4kq..4kq+3][l]
  int lq = blockIdx.x, g = blockIdx.y, n = blockIdx.z;
  int t = threadIdx.x;
  // stage w (global f4 coalesced -> LDS)
  {
    int o = t >> 4, kq = t & 15;
    const float4* qw4 = (const float4*)qw;
    #pragma unroll
    for (int i = 0; i < 8; ++i){
      int oo = o + 16*i;
      wS[oo*17 + kq] = qw4[(g*128 + oo)*16 + kq];
    }
  }
  // decode p: thread t -> l = t>>1, k-half = (t&1)*32
  {
    int l = t >> 1, kh = t & 1;
    unsigned long long sw = sgn [(n*9+g)*1024 + lq*128 + l];
    unsigned long long dw = dimw[(n*9+g)*1024 + lq*128 + l];
    #pragma unroll
    for (int kq = 0; kq < 8; ++kq){
      int kqq = kh*8 + kq;
      float4 v;
      {
        int k = kqq*4;
        float m0 = ((dw>>k)&1ull)?ONE_M_U:1.0f; v.x = ((sw>>k)&1ull)?m0:-m0;
        float m1 = ((dw>>(k+1))&1ull)?ONE_M_U:1.0f; v.y = ((sw>>(k+1))&1ull)?m1:-m1;
        float m2 = ((dw>>(k+2))&1ull)?ONE_M_U:1.0f; v.z = ((sw>>(k+2))&1ull)?m2:-m2;
        float m3 = ((dw>>(k+3))&1ull)?ONE_M_U:1.0f; v.w = ((sw>>(k+3))&1ull)?m3:-m3;
      }
      pS[l*17 + kqq] = v;
    }
  }
  __syncthreads();
  int ot = t >> 4, ltl = t & 15;
  float acc[8][8];
  #pragma unroll
  for (int i = 0; i < 8; ++i)
    #pragma unroll
    for (int j = 0; j < 8; ++j) acc[i][j] = 0.0f;
  for (int kq = 0; kq < 16; ++kq){
    float wr[8][4], pr[8][4];
    #pragma unroll
    for (int i = 0; i < 8; ++i) *(float4*)wr[i] = wS[(ot*8+i)*17 + kq];
    #pragma unroll
    for (int j = 0; j < 8; ++j) *(float4*)pr[j] = pS[(ltl+16*j)*17 + kq];
    #pragma unroll
    for (int e = 0; e < 4; ++e)   // k ascending inside quad
      #pragma unroll
      for (int i = 0; i < 8; ++i)
        #pragma unroll
        for (int j = 0; j < 8; ++j)
          acc[i][j] = __builtin_fmaf(pr[j][e], wr[i][e], acc[i][j]);
  }
  // store lt  (l = lq*128 + ltl + 16j; lanes ltl consecutive -> 64B lines)
  #pragma unroll
  for (int i = 0; i < 8; ++i){
    int o = ot*8 + i;
    float* dst = lt + ((size_t)((n*9+g)*128 + o))*1024 + lq*128 + ltl;
    #pragma unroll
    for (int j = 0; j < 8; ++j) dst[16*j] = acc[i][j];
  }
  // f64 partial sums per o (pass-1 of BN stats)
  double ps[8];
  #pragma unroll
  for (int i = 0; i < 8; ++i){
    double s = 0.0;
    #pragma unroll
    for (int j = 0; j < 8; ++j) s += (double)acc[i][j];
    ps[i] = s;
  }
  __syncthreads();                 // done reading pS; reuse as f64 scratch
  double* red = (double*)pS;       // 128 o x 16 ltl doubles = 16 KB
  #pragma unroll
  for (int i = 0; i < 8; ++i) red[(ot*8+i)*16 + ltl] = ps[i];
  __syncthreads();
  if (t < 128){
    double s = 0.0;
    #pragma unroll
    for (int q = 0; q < 16; ++q) s += red[t*16 + q];
    part[((size_t)g*128 + t)*256 + n*8 + lq] = s;
  }
}

// ================= K_MEAN: reduce pass-1 partials -> f32 mean =================
__global__ __launch_bounds__(64) void k_mean(const double* __restrict__ part,
        float* __restrict__ mv){
  __shared__ double red[64];
  int go = blockIdx.x, t = threadIdx.x;   // go = g*128+o
  double s = 0.0;
  for (int idx = t; idx < 256; idx += 64) s += part[(size_t)go*256 + idx];
  red[t] = s; __syncthreads();
  for (int k = 32; k > 0; k >>= 1){ if (t < k) red[t] += red[t+k]; __syncthreads(); }
  if (t == 0) mv[go*2] = (float)(red[0] / 32768.0);
}

// ================= K_STATS2: pass-2 only (f32 c, c*c bit-identical to r1) ============
__global__ __launch_bounds__(256) void k_stats2(const float* __restrict__ lt,
        float* __restrict__ mv){
  #pragma clang fp contract(off)
  __shared__ double red[256];
  int g = blockIdx.x >> 7, o = blockIdx.x & 127, t = threadIdx.x;
  float mean = mv[(g*128+o)*2];
  double s2 = 0.0;
  for (int n = 0; n < 32; ++n){
    const float* p = lt + ((size_t)((n*9+g)*128 + o)) * 1024;
    for (int j = 0; j < 4; ++j){
      float tv = p[t + j*256];
      float c = tv - mean;
      float sq = c * c;
      s2 += (double)sq;
    }
  }
  red[t] = s2; __syncthreads();
  for (int k = 128; k > 0; k >>= 1){ if (t < k) red[t] += red[t+k]; __syncthreads(); }
  if (t == 0){
    float var = (float)(red[0] / 32768.0);
    float den = __builtin_sqrtf(var + 1e-5f);
    mv[(g*128+o)*2+1] = den;
  }
}

// ================= K_OUT v3: a-outer / g-inner, pointer-walk =================
__global__ __launch_bounds__(256) void k_out_fast(const float* __restrict__ lt,
        const float* __restrict__ mv, const uint32_t* __restrict__ keys,
        const float* __restrict__ gamma, const float* __restrict__ beta,
        float* __restrict__ out){
  #pragma clang fp contract(off)
  __shared__ float    mvL[18];
  __shared__ uint32_t kL[18];
  int bi = blockIdx.x;                  // 4096 = 8 b * 128 o * 4 lc
  int lc = bi & 3, o = (bi >> 2) & 127, b = bi >> 9;
  int t = threadIdx.x;
  if (t < 18){ mvL[t] = mv[((t>>1)*128 + o)*2 + (t&1)]; kL[t] = keys[t]; }
  __syncthreads();
  int l = lc*256 + t;
  float gma = gamma[o], bta = beta[o];
  float S[4];
  #pragma unroll
  for (int a = 0; a < 4; ++a){
    int n = a*8 + b;
#if PRNG_PARTITIONABLE
    uint32_t m = (uint32_t)(n*131072 + o*1024 + l);
#endif
    const float* pa = lt + ((size_t)(n*9)*128 + o)*1024 + l;
    float Sa = 0.0f;
    for (int g = 0; g < 9; ++g){
      float rnd;
#if PRNG_PARTITIONABLE
      uint32_t x0 = 0u, x1 = m;
      threefry2x32(kL[2*g], kL[2*g+1], x0, x1);
      rnd = bits_to_unit(x0 ^ x1);
#else
      // original layout: a01 pairing reconstructed per (a,g)
      uint32_t mm = (uint32_t)(((a&1)*8 + b)*131072 + o*1024 + l);
      uint32_t x0 = mm, x1 = mm + 2097152u;
      threefry2x32(kL[2*g], kL[2*g+1], x0, x1);
      rnd = (a < 2) ? bits_to_unit(x0) : bits_to_unit(x1);
#endif
      float mean = mvL[2*g], den = mvL[2*g+1];
      float tv = pa[g*131072];
      float normed = (tv - mean) / den * gma + bta;
      float th = xla_tanh_f32(4.0f * normed);
      float dec = (th > rnd) ? 1.0f : -1.0f;
      if (normed == 0.0f) dec = 0.0f;
      float cc  = __builtin_fminf(__builtin_fmaxf(normed, -1.0f), 1.0f);
      float fwd = cc + (dec - cc);
      float pre = fwd / 9.0f;
      Sa = Sa + pre;                 // g-ascending chain (as verified)
    }
    S[a] = Sa;
  }
  float z = S[0] * 0.5f;
  z = z + S[1] * 0.25f;
  z = z + S[2] * 0.125f;
  z = z + S[3] * 0.0625f;
  out[(b*128 + o)*1024 + l] = z;
}

// ================= fallback (r1, slow but verified) =================
__global__ __launch_bounds__(256) void k_stats_slow(const float* __restrict__ qw,
        const unsigned long long* __restrict__ sgn, const unsigned long long* __restrict__ dimw,
        float* __restrict__ mv){
  #pragma clang fp contract(off)
  __shared__ double red[256];
  int g = blockIdx.x >> 7, o = blockIdx.x & 127, t = threadIdx.x;
  float wr[64];
  #pragma unroll
  for (int k = 0; k < 64; ++k) wr[k] = qw[(g*128 + o)*64 + k];
  double s1 = 0.0;
  for (int n = 0; n < 32; ++n){
    const unsigned long long* sp = sgn  + (n*9 + g)*1024;
    const unsigned long long* dp = dimw + (n*9 + g)*1024;
    for (int j = 0; j < 4; ++j){
      int l = t + j*256;
      float tv = dot64(sp[l], dp[l], wr);
      s1 += (double)tv;
    }
  }
  red[t] = s1; __syncthreads();
  for (int k = 128; k > 0; k >>= 1){ if (t < k) red[t] += red[t+k]; __syncthreads(); }
  float mean = (float)(red[0] / 32768.0);
  __syncthreads();
  double s2 = 0.0;
  for (int n = 0; n < 32; ++n){
    const unsigned long long* sp = sgn  + (n*9 + g)*1024;
    const unsigned long long* dp = dimw + (n*9 + g)*1024;
    for (int j = 0; j < 4; ++j){
      int l = t + j*256;
      float tv = dot64(sp[l], dp[l], wr);
      float c = tv - mean;
      float sq = c * c;
      s2 += (double)sq;
    }
  }
  red[t] = s2; __syncthreads();
  for (int k = 128; k > 0; k >>= 1){ if (t < k) red[t] += red[t+k]; __syncthreads(); }
  if (t == 0){
    float var = (float)(red[0] / 32768.0);
    float den = __builtin_sqrtf(var + 1e-5f);
    mv[(g*128+o)*2]   = mean;
    mv[(g*128+o)*2+1] = den;
  }
}

__global__ __launch_bounds__(256) void k_out_slow(const float* __restrict__ qw,
        const unsigned long long* __restrict__ sgn, const unsigned long long* __restrict__ dimw,
        const float* __restrict__ mv, const uint32_t* __restrict__ keys,
        const float* __restrict__ gamma, const float* __restrict__ beta,
        float* __restrict__ out){
  #pragma clang fp contract(off)
  __shared__ float    wv[576];
  __shared__ float    mvL[18];
  __shared__ uint32_t kL[18];
  int bi = blockIdx.x;
  int lc = bi & 3, o = (bi >> 2) & 127, b = bi >> 9;
  int t = threadIdx.x;
  for (int j = t; j < 576; j += 256) wv[j] = qw[((j >> 6)*128 + o)*64 + (j & 63)];
  if (t < 18){ mvL[t] = mv[((t>>1)*128 + o)*2 + (t&1)]; kL[t] = keys[t]; }
  __syncthreads();
  int l = lc*256 + t;
  float gma = gamma[o], bta = beta[o];
  float S[4] = {0.0f, 0.0f, 0.0f, 0.0f};
  for (int g = 0; g < 9; ++g){
    float rnd[4];
#if PRNG_PARTITIONABLE
    #pragma unroll
    for (int a = 0; a < 4; ++a){
      uint32_t m = (uint32_t)((a*8 + b)*131072 + o*1024 + l);
      uint32_t x0 = 0u, x1 = m;
      threefry2x32(kL[2*g], kL[2*g+1], x0, x1);
      rnd[a] = bits_to_unit(x0 ^ x1);
    }
#else
    #pragma unroll
    for (int a01 = 0; a01 < 2; ++a01){
      uint32_t m = (uint32_t)((a01*8 + b)*131072 + o*1024 + l);
      uint32_t x0 = m, x1 = m + 2097152u;
      threefry2x32(kL[2*g], kL[2*g+1], x0, x1);
      rnd[a01]     = bits_to_unit(x0);
      rnd[a01 + 2] = bits_to_unit(x1);
    }
#endif
    float mean = mvL[2*g], den = mvL[2*g+1];
    float wr[64];
    #pragma unroll
    for (int k = 0; k < 64; ++k) wr[k] = wv[g*64 + k];
    #pragma unroll
    for (int a = 0; a < 4; ++a){
      int n = a*8 + b;
      float tv = dot64(sgn[(n*9+g)*1024 + l], dimw[(n*9+g)*1024 + l], wr);
      float normed = (tv - mean) / den * gma + bta;
      float th = xla_tanh_f32(4.0f * normed);
      float dec = (th > rnd[a]) ? 1.0f : -1.0f;
      if (normed == 0.0f) dec = 0.0f;
      float cc  = __builtin_fminf(__builtin_fmaxf(normed, -1.0f), 1.0f);
      float fwd = cc + (dec - cc);
      float pre = fwd / 9.0f;
      S[a] = S[a] + pre;
    }
  }
  float z = S[0] * 0.5f;
  z = z + S[1] * 0.25f;
  z = z + S[2] * 0.125f;
  z = z + S[3] * 0.0625f;
  out[(b*128 + o)*1024 + l] = z;
}

extern "C" void kernel_launch(void* const* d_in, const int* in_sizes, int n_in,
                              void* d_out, int out_size, void* d_ws, size_t ws_size,
                              hipStream_t stream){
  (void)in_sizes; (void)n_in; (void)out_size;
  const float* inp   = (const float*)d_in[0];
  const float* wgt   = (const float*)d_in[1];
  const float* gamma = (const float*)d_in[2];
  const float* beta  = (const float*)d_in[3];
  float* out = (float*)d_out;
  char* ws = (char*)d_ws;
  float*              qw   = (float*)(ws + QW_OFF);
  unsigned long long* sgn  = (unsigned long long*)(ws + SGN_OFF);
  unsigned long long* dimw = (unsigned long long*)(ws + DIM_OFF);
  uint32_t*           keys = (uint32_t*)(ws + KEYS_OFF);
  float*              mv   = (float*)(ws + MV_OFF);
  float*              lt   = (float*)(ws + LT_OFF);
  double*             part = (double*)(ws + PART_OFF);

  hipLaunchKernelGGL(k_weights, dim3(128),    dim3(64),  0, stream, wgt, qw, keys);
  hipLaunchKernelGGL(k_stream,  dim3(32, 9),  dim3(256), 0, stream, inp, sgn, dimw);
  if (ws_size >= (size_t)WS_NEEDED_FAST){
    hipLaunchKernelGGL(k_gemm,   dim3(8, 9, 32), dim3(256), 0, stream, qw, sgn, dimw, lt, part);
    hipLaunchKernelGGL(k_mean,   dim3(1152),     dim3(64),  0, stream, part, mv);
    hipLaunchKernelGGL(k_stats2, dim3(1152),     dim3(256), 0, stream, lt, mv);
    hipLaunchKernelGGL(k_out_fast, dim3(4096),   dim3(256), 0, stream, lt, mv, keys,
                       gamma, beta, out);
  } else {
    hipLaunchKernelGGL(k_stats_slow, dim3(1152), dim3(256), 0, stream, qw, sgn, dimw, mv);
    hipLaunchKernelGGL(k_out_slow,   dim3(4096), dim3(256), 0, stream, qw, sgn, dimw, mv, keys,
                       gamma, beta, out);
  }
}